// Round 1
// baseline (1154.827 us; speedup 1.0000x reference)
//
#include <hip/hip_runtime.h>
#include <hip/hip_bf16.h>

// ---------- problem constants ----------
#define TK   8192          // tokens (B*S)
#define DD   1024          // model dim
#define HH   4096          // hidden dim
#define EE   8             // experts
#define BM   128
#define BN   128
#define BK   32
#define MAX_TILES 136      // 2*TK/BM + EE
#define CHUNK_TILES 34     // 4 chunks
#define CHUNK_ROWS (CHUNK_TILES*BM)   // 4352

using s16x8 = __attribute__((ext_vector_type(8))) short;
using f32x4 = __attribute__((ext_vector_type(4))) float;

// meta layout (ints): [0..7]=counts [8..15]=cursor [16]=ntiles [17..25]=tile_start [32..167]=tile_expert
#define META_COUNTS 0
#define META_CURSOR 8
#define META_NTILES 16
#define META_TSTART 17
#define META_TEXP   32

static __device__ __forceinline__ unsigned short f2bf(float f) {
    unsigned u = __builtin_bit_cast(unsigned, f);
    unsigned r = (u + 0x7fffu + ((u >> 16) & 1u)) >> 16;
    return (unsigned short)r;
}

static __device__ __forceinline__ void async_load16(const void* g, void* l) {
    __builtin_amdgcn_global_load_lds(
        (const __attribute__((address_space(1))) unsigned int*)g,
        (__attribute__((address_space(3))) unsigned int*)l, 16, 0, 0);
}

// ---------- small kernels ----------

__global__ void init_meta_k(int* gtok, int* meta) {
    int i = blockIdx.x * 256 + threadIdx.x;
    if (i < MAX_TILES * BM) gtok[i] = -1;
    if (i < 32) meta[i] = 0;
}

// row-wise weight norm -> bf16. one block per row.
__global__ void wn_rows_k(const float* __restrict__ v, const float* __restrict__ g,
                          unsigned short* __restrict__ out, int C) {
    int r = blockIdx.x;
    const float* vr = v + (size_t)r * C;
    float ss = 0.f;
    for (int c = threadIdx.x; c < C; c += 256) { float x = vr[c]; ss += x * x; }
    #pragma unroll
    for (int m = 32; m; m >>= 1) ss += __shfl_xor(ss, m);
    __shared__ float sred[4];
    if ((threadIdx.x & 63) == 0) sred[threadIdx.x >> 6] = ss;
    __syncthreads();
    float tot = sred[0] + sred[1] + sred[2] + sred[3];
    float scale = g[r] / fmaxf(sqrtf(tot), 1e-12f);
    unsigned short* orow = out + (size_t)r * C;
    for (int c = threadIdx.x; c < C; c += 256) orow[c] = f2bf(vr[c] * scale);
}

// gate weight norm in fp64 (top-2 selection must match numpy)
__global__ void wn_gate_k(const float* __restrict__ v, const float* __restrict__ g,
                          double* __restrict__ out) {
    int r = blockIdx.x;
    const float* vr = v + (size_t)r * DD;
    double ss = 0.0;
    for (int c = threadIdx.x; c < DD; c += 256) { double x = (double)vr[c]; ss += x * x; }
    #pragma unroll
    for (int m = 32; m; m >>= 1) ss += __shfl_xor(ss, m);
    __shared__ double sred[4];
    if ((threadIdx.x & 63) == 0) sred[threadIdx.x >> 6] = ss;
    __syncthreads();
    double tot = sred[0] + sred[1] + sred[2] + sred[3];
    double scale = (double)g[r] / fmax(sqrt(tot), 1e-12);
    for (int c = threadIdx.x; c < DD; c += 256) out[(size_t)r * DD + c] = (double)vr[c] * scale;
}

__global__ void x_convert_k(const float* __restrict__ x, unsigned short* __restrict__ xb) {
    size_t i = ((size_t)blockIdx.x * 256 + threadIdx.x) * 4;
    float4 v = *(const float4*)(x + i);
    ushort4 o;
    o.x = f2bf(v.x); o.y = f2bf(v.y); o.z = f2bf(v.z); o.w = f2bf(v.w);
    *(ushort4*)(xb + i) = o;
}

// one wave per token; fp64 logits; write top-2 expert ids
__global__ void gating_k(const float* __restrict__ x, const double* __restrict__ gwn,
                         const float* __restrict__ gb, int* __restrict__ top2) {
    int wave = threadIdx.x >> 6, lane = threadIdx.x & 63;
    int t = blockIdx.x * 4 + wave;
    const float* xr = x + (size_t)t * DD;
    double acc[EE];
    #pragma unroll
    for (int e = 0; e < EE; ++e) acc[e] = 0.0;
    for (int c = 0; c < DD / 64; ++c) {
        double xv = (double)xr[c * 64 + lane];
        #pragma unroll
        for (int e = 0; e < EE; ++e) acc[e] += xv * gwn[(size_t)e * DD + c * 64 + lane];
    }
    #pragma unroll
    for (int e = 0; e < EE; ++e) {
        #pragma unroll
        for (int m = 32; m; m >>= 1) acc[e] += __shfl_xor(acc[e], m);
    }
    if (lane == 0) {
        double lg[EE];
        #pragma unroll
        for (int e = 0; e < EE; ++e) lg[e] = acc[e] + (double)gb[e];
        int b0 = 0;
        #pragma unroll
        for (int e = 1; e < EE; ++e) if (lg[e] > lg[b0]) b0 = e;
        int b1i = (b0 == 0) ? 1 : 0;
        #pragma unroll
        for (int e = 0; e < EE; ++e) if (e != b1i && e != b0 && lg[e] > lg[b1i]) b1i = e;
        top2[t * 2]     = b0;
        top2[t * 2 + 1] = b1i;
    }
}

__global__ void count_experts_k(const int* __restrict__ top2, int* __restrict__ meta) {
    __shared__ int hist[EE];
    if (threadIdx.x < EE) hist[threadIdx.x] = 0;
    __syncthreads();
    int t = blockIdx.x * 256 + threadIdx.x;
    atomicAdd(&hist[top2[t * 2]], 1);
    atomicAdd(&hist[top2[t * 2 + 1]], 1);
    __syncthreads();
    if (threadIdx.x < EE) atomicAdd(&meta[META_COUNTS + threadIdx.x], hist[threadIdx.x]);
}

__global__ void build_tiles_k(int* meta) {
    if (threadIdx.x != 0 || blockIdx.x != 0) return;
    int acc = 0;
    meta[META_TSTART] = 0;
    for (int e = 0; e < EE; ++e) {
        int nt = (meta[META_COUNTS + e] + BM - 1) >> 7;
        for (int k = 0; k < nt; ++k) meta[META_TEXP + acc + k] = e;
        acc += nt;
        meta[META_TSTART + e + 1] = acc;
    }
    meta[META_NTILES] = acc;
}

__global__ void scatter_tokens_k(const int* __restrict__ top2, int* __restrict__ meta,
                                 int* __restrict__ gtok) {
    __shared__ int hist[EE], base[EE];
    if (threadIdx.x < EE) hist[threadIdx.x] = 0;
    __syncthreads();
    int t = blockIdx.x * 256 + threadIdx.x;
    int e0 = top2[t * 2], e1 = top2[t * 2 + 1];
    int p0 = atomicAdd(&hist[e0], 1);
    int p1 = atomicAdd(&hist[e1], 1);
    __syncthreads();
    if (threadIdx.x < EE) base[threadIdx.x] = atomicAdd(&meta[META_CURSOR + threadIdx.x], hist[threadIdx.x]);
    __syncthreads();
    gtok[BM * meta[META_TSTART + e0] + base[e0] + p0] = t;
    gtok[BM * meta[META_TSTART + e1] + base[e1] + p1] = t;
}

// ---------- GEMM1: He = swish(Xg @ W1^T + b1), gathered rows, K=DD ----------
__global__ void gemm1_k(const unsigned short* __restrict__ Xb, const unsigned short* __restrict__ W1,
                        const float* __restrict__ b1, const int* __restrict__ gtok,
                        const int* __restrict__ meta, unsigned short* __restrict__ He,
                        int chunk_base) {
    int t = chunk_base + blockIdx.x;
    if (t >= meta[META_NTILES]) return;
    int e  = meta[META_TEXP + t];
    int n0 = blockIdx.y * BN;
    __shared__ __align__(16) unsigned short As[BM * BK];
    __shared__ __align__(16) unsigned short Bs[BN * BK];
    int tid = threadIdx.x;

    const unsigned short* agp[2];
    const unsigned short* bgp[2];
    #pragma unroll
    for (int r = 0; r < 2; ++r) {
        int flat = r * 256 + tid;
        int arow = flat >> 2, kc = flat & 3;
        int tok = gtok[t * BM + arow]; if (tok < 0) tok = 0;
        agp[r] = Xb + (size_t)tok * DD + kc * 8;
        bgp[r] = W1 + ((size_t)e * HH + n0 + arow) * DD + kc * 8;
    }
    int lane = tid & 63, w = tid >> 6;
    int wm = w >> 1, wn = w & 1;
    int lm = lane & 15, kq = lane >> 4;

    f32x4 acc[4][4] = {};
    for (int k0 = 0; k0 < DD; k0 += BK) {
        __syncthreads();
        #pragma unroll
        for (int r = 0; r < 2; ++r) {
            async_load16(agp[r] + k0, &As[(r * 256 + tid) * 8]);
            async_load16(bgp[r] + k0, &Bs[(r * 256 + tid) * 8]);
        }
        __syncthreads();
        s16x8 af[4], bf[4];
        #pragma unroll
        for (int i = 0; i < 4; ++i) {
            af[i] = *(const s16x8*)&As[(wm * 64 + i * 16 + lm) * BK + kq * 8];
            bf[i] = *(const s16x8*)&Bs[(wn * 64 + i * 16 + lm) * BK + kq * 8];
        }
        #pragma unroll
        for (int i = 0; i < 4; ++i)
            #pragma unroll
            for (int j = 0; j < 4; ++j)
                acc[i][j] = __builtin_amdgcn_mfma_f32_16x16x32_bf16(af[i], bf[j], acc[i][j], 0, 0, 0);
    }
    #pragma unroll
    for (int i = 0; i < 4; ++i) {
        int row = wm * 64 + i * 16 + kq * 4;
        #pragma unroll
        for (int j = 0; j < 4; ++j) {
            int col = n0 + wn * 64 + j * 16 + lm;
            float bb = b1[e * HH + col];
            #pragma unroll
            for (int r = 0; r < 4; ++r) {
                float v = acc[i][j][r] + bb;
                float s = v / (1.0f + __expf(-v));
                He[((size_t)(blockIdx.x * BM + row + r)) * HH + col] = f2bf(s);
            }
        }
    }
}

// ---------- GEMM2: out[tok] += He @ W2^T + b2, K=HH ----------
__global__ void gemm2_k(const unsigned short* __restrict__ He, const unsigned short* __restrict__ W2,
                        const float* __restrict__ b2, const int* __restrict__ gtok,
                        const int* __restrict__ meta, float* __restrict__ out,
                        int chunk_base) {
    int t = chunk_base + blockIdx.x;
    if (t >= meta[META_NTILES]) return;
    int e  = meta[META_TEXP + t];
    int n0 = blockIdx.y * BN;   // cols of DD
    __shared__ __align__(16) unsigned short As[BM * BK];
    __shared__ __align__(16) unsigned short Bs[BN * BK];
    int tid = threadIdx.x;

    const unsigned short* agp[2];
    const unsigned short* bgp[2];
    #pragma unroll
    for (int r = 0; r < 2; ++r) {
        int flat = r * 256 + tid;
        int arow = flat >> 2, kc = flat & 3;
        agp[r] = He + ((size_t)(blockIdx.x * BM + arow)) * HH + kc * 8;
        bgp[r] = W2 + ((size_t)e * DD + n0 + arow) * HH + kc * 8;
    }
    int lane = tid & 63, w = tid >> 6;
    int wm = w >> 1, wn = w & 1;
    int lm = lane & 15, kq = lane >> 4;

    f32x4 acc[4][4] = {};
    for (int k0 = 0; k0 < HH; k0 += BK) {
        __syncthreads();
        #pragma unroll
        for (int r = 0; r < 2; ++r) {
            async_load16(agp[r] + k0, &As[(r * 256 + tid) * 8]);
            async_load16(bgp[r] + k0, &Bs[(r * 256 + tid) * 8]);
        }
        __syncthreads();
        s16x8 af[4], bf[4];
        #pragma unroll
        for (int i = 0; i < 4; ++i) {
            af[i] = *(const s16x8*)&As[(wm * 64 + i * 16 + lm) * BK + kq * 8];
            bf[i] = *(const s16x8*)&Bs[(wn * 64 + i * 16 + lm) * BK + kq * 8];
        }
        #pragma unroll
        for (int i = 0; i < 4; ++i)
            #pragma unroll
            for (int j = 0; j < 4; ++j)
                acc[i][j] = __builtin_amdgcn_mfma_f32_16x16x32_bf16(af[i], bf[j], acc[i][j], 0, 0, 0);
    }
    #pragma unroll
    for (int i = 0; i < 4; ++i) {
        int row = wm * 64 + i * 16 + kq * 4;
        #pragma unroll
        for (int j = 0; j < 4; ++j) {
            int col = n0 + wn * 64 + j * 16 + lm;
            float bb = b2[e * DD + col];
            #pragma unroll
            for (int r = 0; r < 4; ++r) {
                int tok = gtok[t * BM + row + r];
                if (tok >= 0)
                    atomicAdd(&out[(size_t)tok * DD + col], acc[i][j][r] + bb);
            }
        }
    }
}

// ---------- host launch ----------
extern "C" void kernel_launch(void* const* d_in, const int* in_sizes, int n_in,
                              void* d_out, int out_size, void* d_ws, size_t ws_size,
                              hipStream_t stream) {
    const float* x      = (const float*)d_in[0];
    const float* gate_v = (const float*)d_in[1];
    const float* gate_g = (const float*)d_in[2];
    const float* gate_b = (const float*)d_in[3];
    const float* w1_v   = (const float*)d_in[4];
    const float* w1_g   = (const float*)d_in[5];
    const float* b1     = (const float*)d_in[6];
    const float* w2_v   = (const float*)d_in[7];
    const float* w2_g   = (const float*)d_in[8];
    const float* b2     = (const float*)d_in[9];
    float* out = (float*)d_out;

    char* ws = (char*)d_ws;
    size_t off = 0;
    unsigned short* W1n = (unsigned short*)(ws + off); off += (size_t)EE * HH * DD * 2;   // 67MB
    unsigned short* W2n = (unsigned short*)(ws + off); off += (size_t)EE * DD * HH * 2;   // 67MB
    unsigned short* Xb  = (unsigned short*)(ws + off); off += (size_t)TK * DD * 2;        // 16.8MB
    unsigned short* He  = (unsigned short*)(ws + off); off += (size_t)CHUNK_ROWS * HH * 2; // 35.7MB
    double* gwn         = (double*)(ws + off);         off += (size_t)EE * DD * 8;
    int* top2           = (int*)(ws + off);            off += (size_t)TK * 2 * 4;
    int* gtok           = (int*)(ws + off);            off += (size_t)MAX_TILES * BM * 4;
    int* meta           = (int*)(ws + off);            off += 4096;

    hipMemsetAsync(d_out, 0, (size_t)TK * DD * sizeof(float), stream);

    init_meta_k<<<(MAX_TILES * BM) / 256, 256, 0, stream>>>(gtok, meta);
    wn_rows_k<<<EE * HH, 256, 0, stream>>>(w1_v, w1_g, W1n, DD);
    wn_rows_k<<<EE * DD, 256, 0, stream>>>(w2_v, w2_g, W2n, HH);
    wn_gate_k<<<EE, 256, 0, stream>>>(gate_v, gate_g, gwn);
    x_convert_k<<<(TK * DD) / 1024, 256, 0, stream>>>(x, Xb);
    gating_k<<<TK / 4, 256, 0, stream>>>(x, gwn, gate_b, top2);
    count_experts_k<<<TK / 256, 256, 0, stream>>>(top2, meta);
    build_tiles_k<<<1, 64, 0, stream>>>(meta);
    scatter_tokens_k<<<TK / 256, 256, 0, stream>>>(top2, meta, gtok);

    for (int c = 0; c < MAX_TILES / CHUNK_TILES; ++c) {
        gemm1_k<<<dim3(CHUNK_TILES, HH / BN), 256, 0, stream>>>(Xb, W1n, b1, gtok, meta, He, c * CHUNK_TILES);
        gemm2_k<<<dim3(CHUNK_TILES, DD / BN), 256, 0, stream>>>(He, W2n, b2, gtok, meta, out, c * CHUNK_TILES);
    }
}

// Round 2
// 940.288 us; speedup vs baseline: 1.2282x; 1.2282x over previous
//
#include <hip/hip_runtime.h>
#include <hip/hip_bf16.h>

// ---------- problem constants ----------
#define TK   8192          // tokens (B*S)
#define DD   1024          // model dim
#define HH   4096          // hidden dim
#define EE   8             // experts
#define BM   128
#define BN   128
#define BK   32
#define KS   2             // K-split for gemm2
#define MAX_TILES 136      // 2*TK/BM + EE

using s16x8 = __attribute__((ext_vector_type(8))) short;
using f32x4 = __attribute__((ext_vector_type(4))) float;

// meta layout (ints): [0..7]=counts [8..15]=cursor [16]=ntiles [17..25]=tile_start [32..167]=tile_expert
#define META_COUNTS 0
#define META_CURSOR 8
#define META_NTILES 16
#define META_TSTART 17
#define META_TEXP   32

static __device__ __forceinline__ unsigned short f2bf(float f) {
    unsigned u = __builtin_bit_cast(unsigned, f);
    unsigned r = (u + 0x7fffu + ((u >> 16) & 1u)) >> 16;
    return (unsigned short)r;
}

static __device__ __forceinline__ void async_load16(const void* g, void* l) {
    __builtin_amdgcn_global_load_lds(
        (const __attribute__((address_space(1))) unsigned int*)g,
        (__attribute__((address_space(3))) unsigned int*)l, 16, 0, 0);
}

// ---------- small kernels ----------

__global__ void init_meta_k(int* gtok, int* meta) {
    int i = blockIdx.x * 256 + threadIdx.x;
    if (i < MAX_TILES * BM) gtok[i] = -1;
    if (i < 32) meta[i] = 0;
}

// row-wise weight norm -> bf16. one block per row.
__global__ void wn_rows_k(const float* __restrict__ v, const float* __restrict__ g,
                          unsigned short* __restrict__ out, int C) {
    int r = blockIdx.x;
    const float* vr = v + (size_t)r * C;
    float ss = 0.f;
    for (int c = threadIdx.x; c < C; c += 256) { float x = vr[c]; ss += x * x; }
    #pragma unroll
    for (int m = 32; m; m >>= 1) ss += __shfl_xor(ss, m);
    __shared__ float sred[4];
    if ((threadIdx.x & 63) == 0) sred[threadIdx.x >> 6] = ss;
    __syncthreads();
    float tot = sred[0] + sred[1] + sred[2] + sred[3];
    float scale = g[r] / fmaxf(sqrtf(tot), 1e-12f);
    unsigned short* orow = out + (size_t)r * C;
    for (int c = threadIdx.x; c < C; c += 256) orow[c] = f2bf(vr[c] * scale);
}

// gate weight norm in fp64 (top-2 selection must match numpy)
__global__ void wn_gate_k(const float* __restrict__ v, const float* __restrict__ g,
                          double* __restrict__ out) {
    int r = blockIdx.x;
    const float* vr = v + (size_t)r * DD;
    double ss = 0.0;
    for (int c = threadIdx.x; c < DD; c += 256) { double x = (double)vr[c]; ss += x * x; }
    #pragma unroll
    for (int m = 32; m; m >>= 1) ss += __shfl_xor(ss, m);
    __shared__ double sred[4];
    if ((threadIdx.x & 63) == 0) sred[threadIdx.x >> 6] = ss;
    __syncthreads();
    double tot = sred[0] + sred[1] + sred[2] + sred[3];
    double scale = (double)g[r] / fmax(sqrt(tot), 1e-12);
    for (int c = threadIdx.x; c < DD; c += 256) out[(size_t)r * DD + c] = (double)vr[c] * scale;
}

__global__ void x_convert_k(const float* __restrict__ x, unsigned short* __restrict__ xb) {
    size_t i = ((size_t)blockIdx.x * 256 + threadIdx.x) * 4;
    float4 v = *(const float4*)(x + i);
    ushort4 o;
    o.x = f2bf(v.x); o.y = f2bf(v.y); o.z = f2bf(v.z); o.w = f2bf(v.w);
    *(ushort4*)(xb + i) = o;
}

// one wave per token; fp64 logits; write top-2 expert ids
__global__ void gating_k(const float* __restrict__ x, const double* __restrict__ gwn,
                         const float* __restrict__ gb, int* __restrict__ top2) {
    int wave = threadIdx.x >> 6, lane = threadIdx.x & 63;
    int t = blockIdx.x * 4 + wave;
    const float* xr = x + (size_t)t * DD;
    double acc[EE];
    #pragma unroll
    for (int e = 0; e < EE; ++e) acc[e] = 0.0;
    for (int c = 0; c < DD / 64; ++c) {
        double xv = (double)xr[c * 64 + lane];
        #pragma unroll
        for (int e = 0; e < EE; ++e) acc[e] += xv * gwn[(size_t)e * DD + c * 64 + lane];
    }
    #pragma unroll
    for (int e = 0; e < EE; ++e) {
        #pragma unroll
        for (int m = 32; m; m >>= 1) acc[e] += __shfl_xor(acc[e], m);
    }
    if (lane == 0) {
        double lg[EE];
        #pragma unroll
        for (int e = 0; e < EE; ++e) lg[e] = acc[e] + (double)gb[e];
        int b0 = 0;
        #pragma unroll
        for (int e = 1; e < EE; ++e) if (lg[e] > lg[b0]) b0 = e;
        int b1i = (b0 == 0) ? 1 : 0;
        #pragma unroll
        for (int e = 0; e < EE; ++e) if (e != b1i && e != b0 && lg[e] > lg[b1i]) b1i = e;
        top2[t * 2]     = b0;
        top2[t * 2 + 1] = b1i;
    }
}

__global__ void count_experts_k(const int* __restrict__ top2, int* __restrict__ meta) {
    __shared__ int hist[EE];
    if (threadIdx.x < EE) hist[threadIdx.x] = 0;
    __syncthreads();
    int t = blockIdx.x * 256 + threadIdx.x;
    atomicAdd(&hist[top2[t * 2]], 1);
    atomicAdd(&hist[top2[t * 2 + 1]], 1);
    __syncthreads();
    if (threadIdx.x < EE) atomicAdd(&meta[META_COUNTS + threadIdx.x], hist[threadIdx.x]);
}

__global__ void build_tiles_k(int* meta) {
    if (threadIdx.x != 0 || blockIdx.x != 0) return;
    int acc = 0;
    meta[META_TSTART] = 0;
    for (int e = 0; e < EE; ++e) {
        int nt = (meta[META_COUNTS + e] + BM - 1) >> 7;
        for (int k = 0; k < nt; ++k) meta[META_TEXP + acc + k] = e;
        acc += nt;
        meta[META_TSTART + e + 1] = acc;
    }
    meta[META_NTILES] = acc;
}

__global__ void scatter_tokens_k(const int* __restrict__ top2, int* __restrict__ meta,
                                 int* __restrict__ gtok) {
    __shared__ int hist[EE], base[EE];
    if (threadIdx.x < EE) hist[threadIdx.x] = 0;
    __syncthreads();
    int t = blockIdx.x * 256 + threadIdx.x;
    int e0 = top2[t * 2], e1 = top2[t * 2 + 1];
    int p0 = atomicAdd(&hist[e0], 1);
    int p1 = atomicAdd(&hist[e1], 1);
    __syncthreads();
    if (threadIdx.x < EE) base[threadIdx.x] = atomicAdd(&meta[META_CURSOR + threadIdx.x], hist[threadIdx.x]);
    __syncthreads();
    gtok[BM * meta[META_TSTART + e0] + base[e0] + p0] = t;
    gtok[BM * meta[META_TSTART + e1] + base[e1] + p1] = t;
}

// ---------- GEMM1: He = swish(Xg @ W1^T + b1), gathered rows, K=DD ----------
// grid: (HH/BN, chunk_tiles)  -- col-block fastest for A-tile L2 reuse
__global__ void gemm1_k(const unsigned short* __restrict__ Xb, const unsigned short* __restrict__ W1,
                        const float* __restrict__ b1, const int* __restrict__ gtok,
                        const int* __restrict__ meta, unsigned short* __restrict__ He,
                        int chunk_base) {
    int t = chunk_base + blockIdx.y;
    if (t >= meta[META_NTILES]) return;
    int e  = meta[META_TEXP + t];
    int n0 = blockIdx.x * BN;
    __shared__ __align__(16) unsigned short As[BM * BK];
    __shared__ __align__(16) unsigned short Bs[BN * BK];
    int tid = threadIdx.x;

    const unsigned short* agp[2];
    const unsigned short* bgp[2];
    #pragma unroll
    for (int r = 0; r < 2; ++r) {
        int flat = r * 256 + tid;
        int arow = flat >> 2, kc = flat & 3;
        int tok = gtok[t * BM + arow]; if (tok < 0) tok = 0;
        agp[r] = Xb + (size_t)tok * DD + kc * 8;
        bgp[r] = W1 + ((size_t)e * HH + n0 + arow) * DD + kc * 8;
    }
    int lane = tid & 63, w = tid >> 6;
    int wm = w >> 1, wn = w & 1;
    int lm = lane & 15, kq = lane >> 4;

    f32x4 acc[4][4] = {};
    for (int k0 = 0; k0 < DD; k0 += BK) {
        __syncthreads();
        #pragma unroll
        for (int r = 0; r < 2; ++r) {
            async_load16(agp[r] + k0, &As[(r * 256 + tid) * 8]);
            async_load16(bgp[r] + k0, &Bs[(r * 256 + tid) * 8]);
        }
        __syncthreads();
        s16x8 af[4], bf[4];
        #pragma unroll
        for (int i = 0; i < 4; ++i) {
            af[i] = *(const s16x8*)&As[(wm * 64 + i * 16 + lm) * BK + kq * 8];
            bf[i] = *(const s16x8*)&Bs[(wn * 64 + i * 16 + lm) * BK + kq * 8];
        }
        #pragma unroll
        for (int i = 0; i < 4; ++i)
            #pragma unroll
            for (int j = 0; j < 4; ++j)
                acc[i][j] = __builtin_amdgcn_mfma_f32_16x16x32_bf16(af[i], bf[j], acc[i][j], 0, 0, 0);
    }
    #pragma unroll
    for (int i = 0; i < 4; ++i) {
        int row = wm * 64 + i * 16 + kq * 4;
        #pragma unroll
        for (int j = 0; j < 4; ++j) {
            int col = n0 + wn * 64 + j * 16 + lm;
            float bb = b1[e * HH + col];
            #pragma unroll
            for (int r = 0; r < 4; ++r) {
                float v = acc[i][j][r] + bb;
                float s = v / (1.0f + __expf(-v));
                He[((size_t)(blockIdx.y * BM + row + r)) * HH + col] = f2bf(s);
            }
        }
    }
}

// ---------- GEMM2: out[tok] += He @ W2^T + b2, K=HH split by KS ----------
// grid: (DD/BN, chunk_tiles, KS)
__global__ void gemm2_k(const unsigned short* __restrict__ He, const unsigned short* __restrict__ W2,
                        const float* __restrict__ b2, const int* __restrict__ gtok,
                        const int* __restrict__ meta, float* __restrict__ out,
                        int chunk_base) {
    int t = chunk_base + blockIdx.y;
    if (t >= meta[META_NTILES]) return;
    int e  = meta[META_TEXP + t];
    int n0 = blockIdx.x * BN;               // cols of DD
    int kbase = blockIdx.z * (HH / KS);     // K-split range
    __shared__ __align__(16) unsigned short As[BM * BK];
    __shared__ __align__(16) unsigned short Bs[BN * BK];
    int tid = threadIdx.x;

    const unsigned short* agp[2];
    const unsigned short* bgp[2];
    #pragma unroll
    for (int r = 0; r < 2; ++r) {
        int flat = r * 256 + tid;
        int arow = flat >> 2, kc = flat & 3;
        agp[r] = He + ((size_t)(blockIdx.y * BM + arow)) * HH + kbase + kc * 8;
        bgp[r] = W2 + ((size_t)e * DD + n0 + arow) * HH + kbase + kc * 8;
    }
    int lane = tid & 63, w = tid >> 6;
    int wm = w >> 1, wn = w & 1;
    int lm = lane & 15, kq = lane >> 4;

    f32x4 acc[4][4] = {};
    for (int k0 = 0; k0 < HH / KS; k0 += BK) {
        __syncthreads();
        #pragma unroll
        for (int r = 0; r < 2; ++r) {
            async_load16(agp[r] + k0, &As[(r * 256 + tid) * 8]);
            async_load16(bgp[r] + k0, &Bs[(r * 256 + tid) * 8]);
        }
        __syncthreads();
        s16x8 af[4], bf[4];
        #pragma unroll
        for (int i = 0; i < 4; ++i) {
            af[i] = *(const s16x8*)&As[(wm * 64 + i * 16 + lm) * BK + kq * 8];
            bf[i] = *(const s16x8*)&Bs[(wn * 64 + i * 16 + lm) * BK + kq * 8];
        }
        #pragma unroll
        for (int i = 0; i < 4; ++i)
            #pragma unroll
            for (int j = 0; j < 4; ++j)
                acc[i][j] = __builtin_amdgcn_mfma_f32_16x16x32_bf16(af[i], bf[j], acc[i][j], 0, 0, 0);
    }
    bool addb = (blockIdx.z == 0);
    #pragma unroll
    for (int i = 0; i < 4; ++i) {
        int row = wm * 64 + i * 16 + kq * 4;
        #pragma unroll
        for (int j = 0; j < 4; ++j) {
            int col = n0 + wn * 64 + j * 16 + lm;
            float bb = addb ? b2[e * DD + col] : 0.0f;
            #pragma unroll
            for (int r = 0; r < 4; ++r) {
                int tok = gtok[t * BM + row + r];
                if (tok >= 0)
                    atomicAdd(&out[(size_t)tok * DD + col], acc[i][j][r] + bb);
            }
        }
    }
}

// ---------- host launch ----------
extern "C" void kernel_launch(void* const* d_in, const int* in_sizes, int n_in,
                              void* d_out, int out_size, void* d_ws, size_t ws_size,
                              hipStream_t stream) {
    const float* x      = (const float*)d_in[0];
    const float* gate_v = (const float*)d_in[1];
    const float* gate_g = (const float*)d_in[2];
    const float* gate_b = (const float*)d_in[3];
    const float* w1_v   = (const float*)d_in[4];
    const float* w1_g   = (const float*)d_in[5];
    const float* b1     = (const float*)d_in[6];
    const float* w2_v   = (const float*)d_in[7];
    const float* w2_g   = (const float*)d_in[8];
    const float* b2     = (const float*)d_in[9];
    float* out = (float*)d_out;

    char* ws = (char*)d_ws;
    size_t off = 0;
    unsigned short* W1n = (unsigned short*)(ws + off); off += (size_t)EE * HH * DD * 2;   // 67MB
    unsigned short* W2n = (unsigned short*)(ws + off); off += (size_t)EE * DD * HH * 2;   // 67MB
    unsigned short* Xb  = (unsigned short*)(ws + off); off += (size_t)TK * DD * 2;        // 16.8MB
    double* gwn         = (double*)(ws + off);         off += (size_t)EE * DD * 8;
    int* top2           = (int*)(ws + off);            off += (size_t)TK * 2 * 4;
    int* gtok           = (int*)(ws + off);            off += (size_t)MAX_TILES * BM * 4;
    int* meta           = (int*)(ws + off);            off += 4096;
    unsigned short* He  = (unsigned short*)(ws + off); // remaining space

    // dynamic chunking: He tile = BM*HH*2 bytes; use as much workspace as available.
    // deterministic across calls (ws_size constant) -> graph-capture safe.
    size_t he_room = (ws_size > off) ? (ws_size - off) : 0;
    int chunk_tiles = (int)(he_room / ((size_t)BM * HH * 2));
    if (chunk_tiles > MAX_TILES) chunk_tiles = MAX_TILES;
    if (chunk_tiles < 8) chunk_tiles = 8;  // floor (ws_size >= 187MB observed, never hit)
    int nchunks = (MAX_TILES + chunk_tiles - 1) / chunk_tiles;

    hipMemsetAsync(d_out, 0, (size_t)TK * DD * sizeof(float), stream);

    init_meta_k<<<(MAX_TILES * BM) / 256, 256, 0, stream>>>(gtok, meta);
    wn_rows_k<<<EE * HH, 256, 0, stream>>>(w1_v, w1_g, W1n, DD);
    wn_rows_k<<<EE * DD, 256, 0, stream>>>(w2_v, w2_g, W2n, HH);
    wn_gate_k<<<EE, 256, 0, stream>>>(gate_v, gate_g, gwn);
    x_convert_k<<<(TK * DD) / 1024, 256, 0, stream>>>(x, Xb);
    gating_k<<<TK / 4, 256, 0, stream>>>(x, gwn, gate_b, top2);
    count_experts_k<<<TK / 256, 256, 0, stream>>>(top2, meta);
    build_tiles_k<<<1, 64, 0, stream>>>(meta);
    scatter_tokens_k<<<TK / 256, 256, 0, stream>>>(top2, meta, gtok);

    for (int c = 0; c < nchunks; ++c) {
        int base = c * chunk_tiles;
        gemm1_k<<<dim3(HH / BN, chunk_tiles), 256, 0, stream>>>(Xb, W1n, b1, gtok, meta, He, base);
        gemm2_k<<<dim3(DD / BN, chunk_tiles, KS), 256, 0, stream>>>(He, W2n, b2, gtok, meta, out, base);
    }
}